// Round 17
// baseline (187.673 us; speedup 1.0000x reference)
//
#include <hip/hip_runtime.h>

#define N_NODES 100000
#define N_EDGES 1600000
constexpr int BLK = 256;
constexpr int NBKT = (N_NODES + 127) / 128;   // 782 buckets of 128 nodes
constexpr int BCAP = 4096;                    // padded bucket capacity
constexpr int PACK_SHIFT = 17;                // src < 2^17
constexpr int EPT = 16;                       // edges/thread in scatter
constexpr int EPBLK = BLK * EPT;              // 4096
constexpr int NSCAT = (N_EDGES + EPBLK - 1) / EPBLK;   // 391
constexpr int GTILES = N_NODES / 16;          // 6250 gemm<128,64> tiles
constexpr int GHALF = GTILES / 2;             // 3125

// ---------- bf16 helpers (RTNE) ----------
__device__ __forceinline__ unsigned short f2bf(float f) {
    unsigned int u = __float_as_uint(f);
    u = (u + 0x7FFFu + ((u >> 16) & 1u)) >> 16;
    return (unsigned short)u;
}
__device__ __forceinline__ float bf2f(unsigned short s) {
    return __uint_as_float(((unsigned int)s) << 16);
}
__device__ __forceinline__ float bflo(unsigned int u) {
    return __uint_as_float(u << 16);
}
__device__ __forceinline__ float bfhi(unsigned int u) {
    return __uint_as_float(u & 0xffff0000u);
}

// ---------- edge dtype detection (int32 vs int64-lowword) ----------
__global__ void detect_idx64(const unsigned int* __restrict__ e, int* __restrict__ flag) {
    if (blockIdx.x == 0 && threadIdx.x == 0) {
        int is64 = 1;
        for (int i = 0; i < 64; ++i) if (e[2 * i + 1] != 0u) { is64 = 0; break; }
        *flag = is64;
    }
}

__device__ __forceinline__ int load_dst(const int* e, int f, int i) {
    return f ? e[2 * (N_EDGES + i)] : e[N_EDGES + i];
}
__device__ __forceinline__ int load_src(const int* e, int f, int i) {
    return f ? e[2 * i] : e[i];
}

// ---------- helpers ----------
__device__ __forceinline__ void fma_step(float4& acc, float xs, float4 w) {
    acc.x = fmaf(xs, w.x, acc.x);
    acc.y = fmaf(xs, w.y, acc.y);
    acc.z = fmaf(xs, w.z, acc.z);
    acc.w = fmaf(xs, w.w, acc.w);
}
__device__ __forceinline__ void add4(float4& a, float4 v) {
    a.x += v.x; a.y += v.y; a.z += v.z; a.w += v.w;
}
__device__ __forceinline__ void addbf4(float4& a, ushort4 t) {
    a.x += bf2f(t.x); a.y += bf2f(t.y); a.z += bf2f(t.z); a.w += bf2f(t.w);
}

// ---------- device bodies sharing an LDS union ----------

__device__ void scatter_body(const int* __restrict__ eraw, int f,
                             int* __restrict__ cursor, int* __restrict__ ebkt,
                             int bid, void* smem) {
    int* h = (int*)smem;
    const int e0 = bid * EPBLK;
    for (int i = threadIdx.x; i < NBKT; i += BLK) h[i] = 0;
    __syncthreads();
    int bs[EPT], ps[EPT];
#pragma unroll
    for (int k = 0; k < EPT; ++k) {
        const int i = e0 + k * BLK + threadIdx.x;
        if (i < N_EDGES) {
            const int d = load_dst(eraw, f, i);
            const int s = load_src(eraw, f, i);
            bs[k] = d >> 7;
            ps[k] = s | ((d & 127) << PACK_SHIFT);
            atomicAdd(&h[bs[k]], 1);
        } else {
            bs[k] = -1;
            ps[k] = 0;
        }
    }
    __syncthreads();
    for (int b = threadIdx.x; b < NBKT; b += BLK) {
        const int c = h[b];
        if (c) h[b] = atomicAdd(&cursor[b], c);
    }
    __syncthreads();
#pragma unroll
    for (int k = 0; k < EPT; ++k) {
        if (bs[k] >= 0) {
            const int off = atomicAdd(&h[bs[k]], 1);
            ebkt[bs[k] * BCAP + off] = ps[k];
        }
    }
}

__device__ void csrify_body(const int* __restrict__ cnt_b, const int* __restrict__ ebkt,
                            int* __restrict__ adj, int* __restrict__ rowptr,
                            int* __restrict__ deg, int b, void* smem) {
    int* hist = (int*)smem;
    int* excl = hist + 128;
    int* lcur = hist + 256;
    const int s0 = b * BCAP;
    const int s1 = s0 + cnt_b[b];
    for (int i = threadIdx.x; i < 128; i += BLK) hist[i] = 0;
    __syncthreads();
    for (int i = s0 + threadIdx.x; i < s1; i += BLK)
        atomicAdd(&hist[ebkt[i] >> PACK_SHIFT], 1);
    __syncthreads();
    if (threadIdx.x < 128) excl[threadIdx.x] = hist[threadIdx.x];
    __syncthreads();
    for (int off = 1; off < 128; off <<= 1) {
        int t = 0;
        if (threadIdx.x < 128 && threadIdx.x >= off) t = excl[threadIdx.x - off];
        __syncthreads();
        if (threadIdx.x < 128) excl[threadIdx.x] += t;
        __syncthreads();
    }
    if (threadIdx.x < 128) {
        const int e = excl[threadIdx.x] - hist[threadIdx.x];
        lcur[threadIdx.x] = s0 + e;
        const int node = b * 128 + threadIdx.x;
        if (node < N_NODES) {
            rowptr[node] = s0 + e;
            deg[node] = hist[threadIdx.x];
        }
    }
    __syncthreads();
    for (int i = s0 + threadIdx.x; i < s1; i += BLK) {
        const int p = ebkt[i];
        const int pos = atomicAdd(&lcur[p >> PACK_SHIFT], 1);
        adj[pos] = p & ((1 << PACK_SHIFT) - 1);
    }
}

template<int K, int C>
__device__ void gemm_body(const float* __restrict__ X, const float* __restrict__ W,
                          const float* __restrict__ bias, float* __restrict__ Y,
                          unsigned short* __restrict__ Yb, int tile, void* smem) {
    constexpr int CQ = C / 4;
    constexpr int NPB = BLK / CQ;
    constexpr int KQ = K / 4;
    float4* Ws = (float4*)smem;
    float4* xL = Ws + K * CQ;
    for (int i = threadIdx.x; i < K * CQ; i += BLK)
        Ws[i] = reinterpret_cast<const float4*>(W)[i];
    const int cq = threadIdx.x % CQ;
    const int ns = threadIdx.x / CQ;
    const float4 bv = reinterpret_cast<const float4*>(bias)[cq];
    const float4* X4 = reinterpret_cast<const float4*>(X);
    for (int i = threadIdx.x; i < NPB * KQ; i += BLK) {
        const int r = i / KQ;
        const int k4 = i % KQ;
        xL[r * KQ + ((k4 + r) % KQ)] = X4[(size_t)(tile * NPB + r) * KQ + k4];
    }
    __syncthreads();
    const float4* xr = &xL[ns * KQ];
    float4 acc = bv;
#pragma unroll 4
    for (int k4 = 0; k4 < KQ; ++k4) {
        float4 xv = xr[(k4 + ns) % KQ];
        fma_step(acc, xv.x, Ws[(4 * k4 + 0) * CQ + cq]);
        fma_step(acc, xv.y, Ws[(4 * k4 + 1) * CQ + cq]);
        fma_step(acc, xv.z, Ws[(4 * k4 + 2) * CQ + cq]);
        fma_step(acc, xv.w, Ws[(4 * k4 + 3) * CQ + cq]);
    }
    const size_t oi = (size_t)(tile * NPB + ns) * CQ + cq;
    reinterpret_cast<float4*>(Y)[oi] = acc;
    ushort4 bfv;
    bfv.x = f2bf(acc.x); bfv.y = f2bf(acc.y);
    bfv.z = f2bf(acc.z); bfv.w = f2bf(acc.w);
    reinterpret_cast<ushort4*>(Yb)[oi] = bfv;
}

// ---------- fat kernel A: scatter blocks + gemm tiles [0, GHALF) ----------
__global__ void scatter_gemm(const int* __restrict__ eraw, const int* __restrict__ flag,
                             int* __restrict__ cursor, int* __restrict__ ebkt,
                             const float* __restrict__ X, const float* __restrict__ W,
                             const float* __restrict__ bias, float* __restrict__ Y,
                             unsigned short* __restrict__ Yb) {
    __shared__ float4 smem[2560];   // 40960 B union
    if (blockIdx.x < NSCAT) {
        scatter_body(eraw, *flag, cursor, ebkt, blockIdx.x, smem);
    } else {
        gemm_body<128, 64>(X, W, bias, Y, Yb, blockIdx.x - NSCAT, smem);
    }
}

// ---------- fat kernel B: csrify blocks + gemm tiles [GHALF, GTILES) ----------
__global__ void csrify_gemm(const int* __restrict__ cnt_b, const int* __restrict__ ebkt,
                            int* __restrict__ adj, int* __restrict__ rowptr,
                            int* __restrict__ deg,
                            const float* __restrict__ X, const float* __restrict__ W,
                            const float* __restrict__ bias, float* __restrict__ Y,
                            unsigned short* __restrict__ Yb) {
    __shared__ float4 smem[2560];
    if (blockIdx.x < NBKT) {
        csrify_body(cnt_b, ebkt, adj, rowptr, deg, blockIdx.x, smem);
    } else {
        gemm_body<128, 64>(X, W, bias, Y, Yb, GHALF + (int)blockIdx.x - NBKT, smem);
    }
}

// ---------- standalone gemm (conv2 lin2) ----------
template<int K, int C>
__global__ void gemm_bias(const float* __restrict__ X, const float* __restrict__ W,
                          const float* __restrict__ bias, float* __restrict__ Y,
                          unsigned short* __restrict__ Yb, int n) {
    constexpr int CQ = C / 4;
    constexpr int NPB = BLK / CQ;
    constexpr int KQ = K / 4;
    __shared__ float4 Ws[K * CQ];
    __shared__ float4 xL[NPB * KQ];
    for (int i = threadIdx.x; i < K * CQ; i += BLK)
        Ws[i] = reinterpret_cast<const float4*>(W)[i];
    const int cq = threadIdx.x % CQ;
    const int ns = threadIdx.x / CQ;
    const float4 bv = reinterpret_cast<const float4*>(bias)[cq];
    const float4* X4 = reinterpret_cast<const float4*>(X);
    const int tile = blockIdx.x;
    for (int i = threadIdx.x; i < NPB * KQ; i += BLK) {
        const int r = i / KQ;
        const int k4 = i % KQ;
        xL[r * KQ + ((k4 + r) % KQ)] = X4[(size_t)(tile * NPB + r) * KQ + k4];
    }
    __syncthreads();
    const float4* xr = &xL[ns * KQ];
    float4 acc = bv;
#pragma unroll 4
    for (int k4 = 0; k4 < KQ; ++k4) {
        float4 xv = xr[(k4 + ns) % KQ];
        fma_step(acc, xv.x, Ws[(4 * k4 + 0) * CQ + cq]);
        fma_step(acc, xv.y, Ws[(4 * k4 + 1) * CQ + cq]);
        fma_step(acc, xv.z, Ws[(4 * k4 + 2) * CQ + cq]);
        fma_step(acc, xv.w, Ws[(4 * k4 + 3) * CQ + cq]);
    }
    const size_t oi = (size_t)(tile * NPB + ns) * CQ + cq;
    reinterpret_cast<float4*>(Y)[oi] = acc;
    ushort4 bfv;
    bfv.x = f2bf(acc.x); bfv.y = f2bf(acc.y);
    bfv.z = f2bf(acc.z); bfv.w = f2bf(acc.w);
    reinterpret_cast<ushort4*>(Yb)[oi] = bfv;
}

// ---------- conv1 update: CQ=8 lanes/node, 16B row loads, cooperative adj ----------
// TPB=512, NPB=64. Ws 32KB + Ag 17.4KB -> 3 blocks/CU. Lane owns 8 channels (quads 2cq, 2cq+1).
template<int TPB>
__global__ void update_gather_w(const float* __restrict__ P,
                                const unsigned short* __restrict__ Pb,
                                const int* __restrict__ rowptr, const int* __restrict__ cnt,
                                const int* __restrict__ adj,
                                const float* __restrict__ W, const float* __restrict__ bias,
                                float* __restrict__ Y, int n) {
    constexpr int CQ = 8;               // lanes per node
    constexpr int NPB = TPB / CQ;       // 64 nodes per block
    constexpr int QROW = 16;            // float4 quads per 64-ch row
    constexpr int K = 128;
    __shared__ float4 Ws[K * QROW];     // 32 KB
    __shared__ float4 Ag[NPB][QROW + 1];
    for (int i = threadIdx.x; i < K * QROW; i += TPB)
        Ws[i] = reinterpret_cast<const float4*>(W)[i];
    __syncthreads();
    const int cq = threadIdx.x & 7;
    const int ns = threadIdx.x >> 3;
    const int nodeRaw = blockIdx.x * NPB + ns;
    const bool active = nodeRaw < n;
    const int node = active ? nodeRaw : (n - 1);
    const int start = rowptr[node];
    const int deg = cnt[node];
    const float inv = 1.0f / (float)(deg + 1);
    const float4* pr = reinterpret_cast<const float4*>(P) + (size_t)node * QROW;
    const uint4* Pb16 = reinterpret_cast<const uint4*>(Pb);

    float ag0 = 0.f, ag1 = 0.f, ag2 = 0.f, ag3 = 0.f;
    float ag4 = 0.f, ag5 = 0.f, ag6 = 0.f, ag7 = 0.f;
    const int dmain = deg & ~7;
    int j = 0;
    for (; j < dmain; j += 8) {
        const int idx = adj[start + j + cq];
        const int s0 = __shfl(idx, 0, 8);
        const int s1 = __shfl(idx, 1, 8);
        const int s2 = __shfl(idx, 2, 8);
        const int s3 = __shfl(idx, 3, 8);
        const int s4 = __shfl(idx, 4, 8);
        const int s5 = __shfl(idx, 5, 8);
        const int s6 = __shfl(idx, 6, 8);
        const int s7 = __shfl(idx, 7, 8);
        const uint4 t0 = Pb16[(size_t)s0 * 8 + cq];
        const uint4 t1 = Pb16[(size_t)s1 * 8 + cq];
        const uint4 t2 = Pb16[(size_t)s2 * 8 + cq];
        const uint4 t3 = Pb16[(size_t)s3 * 8 + cq];
        const uint4 t4 = Pb16[(size_t)s4 * 8 + cq];
        const uint4 t5 = Pb16[(size_t)s5 * 8 + cq];
        const uint4 t6 = Pb16[(size_t)s6 * 8 + cq];
        const uint4 t7 = Pb16[(size_t)s7 * 8 + cq];
#define ACC(t) do { \
        ag0 += bflo((t).x); ag1 += bfhi((t).x); \
        ag2 += bflo((t).y); ag3 += bfhi((t).y); \
        ag4 += bflo((t).z); ag5 += bfhi((t).z); \
        ag6 += bflo((t).w); ag7 += bfhi((t).w); } while (0)
        ACC(t0); ACC(t1); ACC(t2); ACC(t3);
        ACC(t4); ACC(t5); ACC(t6); ACC(t7);
    }
    if (j < deg) {
        const int rem = deg - j;
        const int idx = (cq < rem) ? adj[start + j + cq] : 0;
        for (int k = 0; k < rem; ++k) {
            const int s = __shfl(idx, k, 8);
            const uint4 t = Pb16[(size_t)s * 8 + cq];
            ACC(t);
        }
    }
#undef ACC

    float4 acc0 = reinterpret_cast<const float4*>(bias)[2 * cq];
    float4 acc1 = reinterpret_cast<const float4*>(bias)[2 * cq + 1];
#pragma unroll 4
    for (int k4 = 0; k4 < QROW; ++k4) {
        const float4 pv = pr[k4];
        fma_step(acc0, pv.x, Ws[(4 * k4 + 0) * QROW + 2 * cq]);
        fma_step(acc1, pv.x, Ws[(4 * k4 + 0) * QROW + 2 * cq + 1]);
        fma_step(acc0, pv.y, Ws[(4 * k4 + 1) * QROW + 2 * cq]);
        fma_step(acc1, pv.y, Ws[(4 * k4 + 1) * QROW + 2 * cq + 1]);
        fma_step(acc0, pv.z, Ws[(4 * k4 + 2) * QROW + 2 * cq]);
        fma_step(acc1, pv.z, Ws[(4 * k4 + 2) * QROW + 2 * cq + 1]);
        fma_step(acc0, pv.w, Ws[(4 * k4 + 3) * QROW + 2 * cq]);
        fma_step(acc1, pv.w, Ws[(4 * k4 + 3) * QROW + 2 * cq + 1]);
    }
    {
        const float4 pv0 = pr[2 * cq];
        const float4 pv1 = pr[2 * cq + 1];
        float4 a0, a1;
        a0.x = (ag0 + pv0.x) * inv; a0.y = (ag1 + pv0.y) * inv;
        a0.z = (ag2 + pv0.z) * inv; a0.w = (ag3 + pv0.w) * inv;
        a1.x = (ag4 + pv1.x) * inv; a1.y = (ag5 + pv1.y) * inv;
        a1.z = (ag6 + pv1.z) * inv; a1.w = (ag7 + pv1.w) * inv;
        Ag[ns][2 * cq] = a0;
        Ag[ns][2 * cq + 1] = a1;
    }
    __syncthreads();
#pragma unroll 4
    for (int k4 = 0; k4 < QROW; ++k4) {
        const float4 av = Ag[ns][k4];
        fma_step(acc0, av.x, Ws[(64 + 4 * k4 + 0) * QROW + 2 * cq]);
        fma_step(acc1, av.x, Ws[(64 + 4 * k4 + 0) * QROW + 2 * cq + 1]);
        fma_step(acc0, av.y, Ws[(64 + 4 * k4 + 1) * QROW + 2 * cq]);
        fma_step(acc1, av.y, Ws[(64 + 4 * k4 + 1) * QROW + 2 * cq + 1]);
        fma_step(acc0, av.z, Ws[(64 + 4 * k4 + 2) * QROW + 2 * cq]);
        fma_step(acc1, av.z, Ws[(64 + 4 * k4 + 2) * QROW + 2 * cq + 1]);
        fma_step(acc0, av.w, Ws[(64 + 4 * k4 + 3) * QROW + 2 * cq]);
        fma_step(acc1, av.w, Ws[(64 + 4 * k4 + 3) * QROW + 2 * cq + 1]);
    }
    acc0.x = fmaxf(acc0.x, 0.f); acc0.y = fmaxf(acc0.y, 0.f);
    acc0.z = fmaxf(acc0.z, 0.f); acc0.w = fmaxf(acc0.w, 0.f);
    acc1.x = fmaxf(acc1.x, 0.f); acc1.y = fmaxf(acc1.y, 0.f);
    acc1.z = fmaxf(acc1.z, 0.f); acc1.w = fmaxf(acc1.w, 0.f);
    if (active) {
        float4* Y4 = reinterpret_cast<float4*>(Y) + (size_t)nodeRaw * QROW;
        Y4[2 * cq] = acc0;
        Y4[2 * cq + 1] = acc1;
    }
}

// ---------- conv2 update (bf16 ushort4 gather) fused with final 32->1 linear ----------
__global__ void update2_final(const float* __restrict__ P,
                              const unsigned short* __restrict__ Pb,
                              const int* __restrict__ rowptr, const int* __restrict__ cnt,
                              const int* __restrict__ adj,
                              const float* __restrict__ W, const float* __restrict__ bias,
                              const float* __restrict__ Wl, const float* __restrict__ bl,
                              float* __restrict__ out, int n) {
    constexpr int CQ = 8;
    constexpr int NPB = BLK / CQ;
    __shared__ float4 Ws[64 * CQ];
    __shared__ float4 Ag[NPB][CQ + 1];
    for (int i = threadIdx.x; i < 64 * CQ; i += BLK)
        Ws[i] = reinterpret_cast<const float4*>(W)[i];
    __syncthreads();
    const int cq = threadIdx.x % CQ;
    const int ns = threadIdx.x / CQ;
    const float4 bv = reinterpret_cast<const float4*>(bias)[cq];
    const float4 wlv = reinterpret_cast<const float4*>(Wl)[cq];
    const float blv = bl[0];
    const float4* P4 = reinterpret_cast<const float4*>(P);
    const ushort4* Pb4 = reinterpret_cast<const ushort4*>(Pb);
    const int node = blockIdx.x * NPB + ns;
    const int start = rowptr[node];
    const int deg = cnt[node];
    const float inv = 1.0f / (float)(deg + 1);
    const float4* pr = &P4[(size_t)node * CQ];

    float4 agg = {0.f, 0.f, 0.f, 0.f};
    int j = 0;
    for (; j + 7 < deg; j += 8) {
        const int s0 = adj[start + j];
        const int s1 = adj[start + j + 1];
        const int s2 = adj[start + j + 2];
        const int s3 = adj[start + j + 3];
        const int s4 = adj[start + j + 4];
        const int s5 = adj[start + j + 5];
        const int s6 = adj[start + j + 6];
        const int s7 = adj[start + j + 7];
        const ushort4 t0 = Pb4[(size_t)s0 * CQ + cq];
        const ushort4 t1 = Pb4[(size_t)s1 * CQ + cq];
        const ushort4 t2 = Pb4[(size_t)s2 * CQ + cq];
        const ushort4 t3 = Pb4[(size_t)s3 * CQ + cq];
        const ushort4 t4 = Pb4[(size_t)s4 * CQ + cq];
        const ushort4 t5 = Pb4[(size_t)s5 * CQ + cq];
        const ushort4 t6 = Pb4[(size_t)s6 * CQ + cq];
        const ushort4 t7 = Pb4[(size_t)s7 * CQ + cq];
        addbf4(agg, t0); addbf4(agg, t1); addbf4(agg, t2); addbf4(agg, t3);
        addbf4(agg, t4); addbf4(agg, t5); addbf4(agg, t6); addbf4(agg, t7);
    }
    if (j + 3 < deg) {
        const int s0 = adj[start + j];
        const int s1 = adj[start + j + 1];
        const int s2 = adj[start + j + 2];
        const int s3 = adj[start + j + 3];
        const ushort4 t0 = Pb4[(size_t)s0 * CQ + cq];
        const ushort4 t1 = Pb4[(size_t)s1 * CQ + cq];
        const ushort4 t2 = Pb4[(size_t)s2 * CQ + cq];
        const ushort4 t3 = Pb4[(size_t)s3 * CQ + cq];
        addbf4(agg, t0); addbf4(agg, t1); addbf4(agg, t2); addbf4(agg, t3);
        j += 4;
    }
    for (; j < deg; ++j)
        addbf4(agg, Pb4[(size_t)adj[start + j] * CQ + cq]);

    float4 acc = bv;
#pragma unroll
    for (int k4 = 0; k4 < 8; ++k4) {
        float4 pv = pr[k4];
        fma_step(acc, pv.x, Ws[(4 * k4 + 0) * CQ + cq]);
        fma_step(acc, pv.y, Ws[(4 * k4 + 1) * CQ + cq]);
        fma_step(acc, pv.z, Ws[(4 * k4 + 2) * CQ + cq]);
        fma_step(acc, pv.w, Ws[(4 * k4 + 3) * CQ + cq]);
    }
    {
        float4 pv = pr[cq];
        add4(agg, pv);
        agg.x *= inv; agg.y *= inv; agg.z *= inv; agg.w *= inv;
    }
    Ag[ns][cq] = agg;
    __syncthreads();
#pragma unroll
    for (int k4 = 0; k4 < 8; ++k4) {
        float4 av = Ag[ns][k4];
        fma_step(acc, av.x, Ws[(32 + 4 * k4 + 0) * CQ + cq]);
        fma_step(acc, av.y, Ws[(32 + 4 * k4 + 1) * CQ + cq]);
        fma_step(acc, av.z, Ws[(32 + 4 * k4 + 2) * CQ + cq]);
        fma_step(acc, av.w, Ws[(32 + 4 * k4 + 3) * CQ + cq]);
    }
    float v = fmaxf(acc.x, 0.0f) * wlv.x + fmaxf(acc.y, 0.0f) * wlv.y
            + fmaxf(acc.z, 0.0f) * wlv.z + fmaxf(acc.w, 0.0f) * wlv.w;
    v += __shfl_xor(v, 4, 8);
    v += __shfl_xor(v, 2, 8);
    v += __shfl_xor(v, 1, 8);
    if (cq == 0) out[node] = v + blv;
}

extern "C" void kernel_launch(void* const* d_in, const int* in_sizes, int n_in,
                              void* d_out, int out_size, void* d_ws, size_t ws_size,
                              hipStream_t stream) {
    const float* x    = (const float*)d_in[0];
    const int*   eraw = (const int*)d_in[1];
    const float* W2_1 = (const float*)d_in[2];
    const float* b2_1 = (const float*)d_in[3];
    const float* W1_1 = (const float*)d_in[4];
    const float* b1_1 = (const float*)d_in[5];
    const float* W2_2 = (const float*)d_in[6];
    const float* b2_2 = (const float*)d_in[7];
    const float* W1_2 = (const float*)d_in[8];
    const float* b1_2 = (const float*)d_in[9];
    const float* Wl   = (const float*)d_in[10];
    const float* bl   = (const float*)d_in[11];
    float* out = (float*)d_out;

    // workspace layout (~97 MB)
    char* ws = (char*)d_ws;
    int* flag   = (int*)ws;
    size_t off = 256;
    int* cursor = (int*)(ws + off); off += sizeof(int) * (size_t)(NBKT + 2);
    off = (off + 255) & ~(size_t)255;
    int* ebkt   = (int*)(ws + off); off += sizeof(int) * (size_t)NBKT * BCAP;  // 12.8 MB
    off = (off + 255) & ~(size_t)255;
    int* adj    = (int*)(ws + off); off += sizeof(int) * (size_t)NBKT * BCAP;  // 12.8 MB
    int* rowptr = (int*)(ws + off); off += sizeof(int) * (size_t)N_NODES;
    int* deg    = (int*)(ws + off); off += sizeof(int) * (size_t)N_NODES;
    off = (off + 255) & ~(size_t)255;
    float* bufA = (float*)(ws + off); off += sizeof(float) * (size_t)N_NODES * 64;  // 25.6 MB
    float* bufC = (float*)(ws + off); off += sizeof(float) * (size_t)N_NODES * 64;  // 25.6 MB
    unsigned short* bufAb = (unsigned short*)(ws + off);
    off += sizeof(unsigned short) * (size_t)N_NODES * 64;                           // 12.8 MB

    hipMemsetAsync(cursor, 0, sizeof(int) * (size_t)(NBKT + 2), stream);

    detect_idx64<<<1, 64, 0, stream>>>((const unsigned int*)eraw, flag);

    // fat A: edge scatter overlapped with gemm tiles [0, GHALF)
    scatter_gemm<<<NSCAT + GHALF, BLK, 0, stream>>>(eraw, flag, cursor, ebkt,
                                                    x, W2_1, b2_1, bufA, bufAb);
    // fat B: csrify overlapped with gemm tiles [GHALF, GTILES)
    csrify_gemm<<<NBKT + GHALF, BLK, 0, stream>>>(cursor, ebkt, adj, rowptr, deg,
                                                  x, W2_1, b2_1, bufA, bufAb);

    // conv1 update (instruction-thin gather: 16B row loads + cooperative adj)
    update_gather_w<512><<<(N_NODES + 63) / 64, 512, 0, stream>>>(
        bufA, bufAb, rowptr, deg, adj, W1_1, b1_1, bufC, N_NODES);

    // conv2 (reuse bufA fp32 + bufAb bf16 for h2pre)
    gemm_bias<64, 32><<<N_NODES / 32, BLK, 0, stream>>>(bufC, W2_2, b2_2, bufA, bufAb, N_NODES);
    update2_final<<<N_NODES / 32, BLK, 0, stream>>>(bufA, bufAb, rowptr, deg, adj, W1_2, b1_2, Wl, bl, out, N_NODES);
}